// Round 19
// baseline (310.214 us; speedup 1.0000x reference)
//
#include <hip/hip_runtime.h>

using short8 = __attribute__((ext_vector_type(8))) short;
using f32x4  = __attribute__((ext_vector_type(4))) float;

constexpr int HD = 128;
constexpr int NBLK_SCAT = 4096;   // scatter (deg/fill) blocks: 8 XCD groups x 512

__device__ __forceinline__ unsigned short f2bf(float f) {
    unsigned u = __builtin_bit_cast(unsigned, f);
    u += 0x7fffu + ((u >> 16) & 1u);          // round-to-nearest-even
    return (unsigned short)(u >> 16);
}
__device__ __forceinline__ float bflo(unsigned u) { return __builtin_bit_cast(float, u << 16); }
__device__ __forceinline__ float bfhi(unsigned u) { return __builtin_bit_cast(float, u & 0xffff0000u); }

__device__ __forceinline__ short8 ldg8(const unsigned short* p) {
    return *reinterpret_cast<const short8*>(p);   // 16B contiguous, aligned
}

// ---------------------------------------------------------------------------
// Chain GEMM body: Out = (relu(A @ Wt1 + b1)) @ Wtc + b2. 64 rows x 128 cols.
// Output staged into As1 (dead after phase 1), coalesced uint4 write-out.
// ---------------------------------------------------------------------------
__device__ __forceinline__ void dev_chain(unsigned short* As1, unsigned short* Hs,
    const unsigned short* __restrict__ A, const unsigned short* __restrict__ Wt1,
    const unsigned short* __restrict__ Wtc, const float* __restrict__ b1,
    const float* __restrict__ b2, unsigned short* __restrict__ Out, int nrows, int bid)
{
    const int tid  = threadIdx.x;
    const int lane = tid & 63, wave = tid >> 6;
    const int lr = lane & 15, lg = lane >> 4;
    const int row0 = bid * 64;

#pragma unroll
    for (int it = 0; it < 4; ++it) {
        const int q   = wave * 4 + it;
        const int c   = q * 64 + lane;
        const int row = c >> 4, cw = c & 15;
        int grow = row0 + row; grow = grow < nrows ? grow : nrows - 1;
        const int gco = (cw ^ (row & 7)) << 3;
        __builtin_amdgcn_global_load_lds((const unsigned int*)(A + (long)grow * HD + gco),
                                         (unsigned int*)&As1[q * 512], 16, 0, 0);
    }

    const int cb = wave * 32;
    short8 bf1[2][4];
#pragma unroll
    for (int ct = 0; ct < 2; ++ct) {
        const unsigned short* bp = Wt1 + (long)(cb + ct * 16 + lr) * HD + lg * 8;
#pragma unroll
        for (int kt = 0; kt < 4; ++kt) bf1[ct][kt] = ldg8(bp + kt * 32);
    }
    short8 bfc[2][4];
#pragma unroll
    for (int ct = 0; ct < 2; ++ct) {
        const unsigned short* bp = Wtc + (long)(cb + ct * 16 + lr) * HD + lg * 8;
#pragma unroll
        for (int kt = 0; kt < 4; ++kt) bfc[ct][kt] = ldg8(bp + kt * 32);
    }

    __syncthreads();   // (1) DMA + weights drained

    f32x4 acc[4][2] = {};
#pragma unroll
    for (int kt = 0; kt < 4; ++kt) {
        short8 af[4];
#pragma unroll
        for (int rt = 0; rt < 4; ++rt)
            af[rt] = *reinterpret_cast<const short8*>(
                &As1[(rt * 16 + lr) * HD + (((kt * 4 + lg) ^ (lr & 7)) << 3)]);
#pragma unroll
        for (int rt = 0; rt < 4; ++rt)
#pragma unroll
            for (int ct = 0; ct < 2; ++ct)
                acc[rt][ct] = __builtin_amdgcn_mfma_f32_16x16x32_bf16(af[rt], bf1[ct][kt], acc[rt][ct], 0, 0, 0);
    }

    const float bv1[2] = { b1[cb + lr], b1[cb + 16 + lr] };
#pragma unroll
    for (int rt = 0; rt < 4; ++rt)
#pragma unroll
        for (int ct = 0; ct < 2; ++ct) {
            const int cc = cb + ct * 16 + lr;
#pragma unroll
            for (int i = 0; i < 4; ++i) {
                const int row = rt * 16 + lg * 4 + i;
                const float v = fmaxf(acc[rt][ct][i] + bv1[ct], 0.f);
                Hs[row * HD + ((((cc >> 3) ^ (row & 7)) << 3) | (cc & 7))] = f2bf(v);
            }
        }
    __syncthreads();   // (2) h visible; As1 reads all done

    f32x4 acc2[4][2] = {};
#pragma unroll
    for (int kt = 0; kt < 4; ++kt) {
        short8 ah[4];
#pragma unroll
        for (int rt = 0; rt < 4; ++rt)
            ah[rt] = *reinterpret_cast<const short8*>(
                &Hs[(rt * 16 + lr) * HD + (((kt * 4 + lg) ^ (lr & 7)) << 3)]);
#pragma unroll
        for (int rt = 0; rt < 4; ++rt)
#pragma unroll
            for (int ct = 0; ct < 2; ++ct)
                acc2[rt][ct] = __builtin_amdgcn_mfma_f32_16x16x32_bf16(ah[rt], bfc[ct][kt], acc2[rt][ct], 0, 0, 0);
    }
    const float bv2[2] = { b2[cb + lr], b2[cb + 16 + lr] };
#pragma unroll
    for (int rt = 0; rt < 4; ++rt)
#pragma unroll
        for (int ct = 0; ct < 2; ++ct) {
            const int cc = cb + ct * 16 + lr;
#pragma unroll
            for (int i = 0; i < 4; ++i) {
                const int row = rt * 16 + lg * 4 + i;
                As1[row * HD + ((((cc >> 3) ^ (row & 7)) << 3) | (cc & 7))] = f2bf(acc2[rt][ct][i] + bv2[ct]);
            }
        }
    __syncthreads();   // (3) staged output visible

#pragma unroll
    for (int k = 0; k < 4; ++k) {
        const int c   = tid + k * 256;
        const int row = c >> 4, cw = c & 15;
        const int r = row0 + row;
        if (r < nrows) {
            const uint4 v = *reinterpret_cast<const uint4*>(
                &As1[row * HD + ((cw ^ (row & 7)) << 3)]);
            *reinterpret_cast<uint4*>(Out + (long)r * HD + cw * 8) = v;
        }
    }
}

__global__ __launch_bounds__(256)
void k_chain(const unsigned short* __restrict__ A, const unsigned short* __restrict__ Wt1,
             const unsigned short* __restrict__ Wtc, const float* __restrict__ b1,
             const float* __restrict__ b2, unsigned short* __restrict__ Out, int nrows)
{
    __shared__ __align__(16) unsigned short As1[64 * HD];
    __shared__ __align__(16) unsigned short Hs [64 * HD];
    dev_chain(As1, Hs, A, Wt1, Wtc, b1, b2, Out, nrows, blockIdx.x);
}

// ---------------------------------------------------------------------------
// Dual GEMM (unfused): Xout = relu(Agg@WtL + X@WtR + bl). 64 rows, 2 LDS
// buffers (32KB -> 5 blocks/CU), ONE MFMA phase, staged coalesced epilogue.
// ---------------------------------------------------------------------------
__global__ __launch_bounds__(256)
void k_dual(const unsigned short* __restrict__ Agg, const unsigned short* __restrict__ X,
            const unsigned short* __restrict__ WtL, const unsigned short* __restrict__ WtR,
            const float* __restrict__ bl_, unsigned short* __restrict__ Xout, int n)
{
    __shared__ __align__(16) unsigned short Ag[64 * HD];
    __shared__ __align__(16) unsigned short Xs[64 * HD];

    const int tid  = threadIdx.x;
    const int lane = tid & 63, wave = tid >> 6;
    const int lr = lane & 15, lg = lane >> 4;
    const int row0 = blockIdx.x * 64;

#pragma unroll
    for (int it = 0; it < 4; ++it) {
        const int q   = wave * 4 + it;
        const int c   = q * 64 + lane;
        const int row = c >> 4, cw = c & 15;
        int grow = row0 + row; grow = grow < n ? grow : n - 1;
        const int gco = (cw ^ (row & 7)) << 3;
        __builtin_amdgcn_global_load_lds((const unsigned int*)(Agg + (long)grow * HD + gco),
                                         (unsigned int*)&Ag[q * 512], 16, 0, 0);
        __builtin_amdgcn_global_load_lds((const unsigned int*)(X + (long)grow * HD + gco),
                                         (unsigned int*)&Xs[q * 512], 16, 0, 0);
    }

    const int cb = wave * 32;
    short8 bl[2][4], br[2][4];
#pragma unroll
    for (int ct = 0; ct < 2; ++ct) {
        const unsigned short* pl = WtL + (long)(cb + ct * 16 + lr) * HD + lg * 8;
        const unsigned short* pr = WtR + (long)(cb + ct * 16 + lr) * HD + lg * 8;
#pragma unroll
        for (int kt = 0; kt < 4; ++kt) { bl[ct][kt] = ldg8(pl + kt * 32); br[ct][kt] = ldg8(pr + kt * 32); }
    }
    __syncthreads();   // (1) DMA + weights drained

    f32x4 acc[4][2] = {};
#pragma unroll
    for (int kt = 0; kt < 4; ++kt) {
        short8 aa[4], ax[4];
#pragma unroll
        for (int rt = 0; rt < 4; ++rt) {
            const int base = (rt * 16 + lr) * HD + (((kt * 4 + lg) ^ (lr & 7)) << 3);
            aa[rt] = *reinterpret_cast<const short8*>(&Ag[base]);
            ax[rt] = *reinterpret_cast<const short8*>(&Xs[base]);
        }
#pragma unroll
        for (int rt = 0; rt < 4; ++rt)
#pragma unroll
            for (int ct = 0; ct < 2; ++ct) {
                acc[rt][ct] = __builtin_amdgcn_mfma_f32_16x16x32_bf16(aa[rt], bl[ct][kt], acc[rt][ct], 0, 0, 0);
                acc[rt][ct] = __builtin_amdgcn_mfma_f32_16x16x32_bf16(ax[rt], br[ct][kt], acc[rt][ct], 0, 0, 0);
            }
    }
    __syncthreads();   // (2) all Ag/Xs reads done

    const float bv[2] = { bl_[cb + lr], bl_[cb + 16 + lr] };
#pragma unroll
    for (int rt = 0; rt < 4; ++rt)
#pragma unroll
        for (int ct = 0; ct < 2; ++ct) {
            const int cc = cb + ct * 16 + lr;
#pragma unroll
            for (int i = 0; i < 4; ++i) {
                const int row = rt * 16 + lg * 4 + i;
                const float v = fmaxf(acc[rt][ct][i] + bv[ct], 0.f);
                Ag[row * HD + ((((cc >> 3) ^ (row & 7)) << 3) | (cc & 7))] = f2bf(v);
            }
        }
    __syncthreads();   // (3) staged output visible

#pragma unroll
    for (int k = 0; k < 4; ++k) {
        const int c   = tid + k * 256;
        const int row = c >> 4, cw = c & 15;
        const int r = row0 + row;
        if (r < n) {
            const uint4 v = *reinterpret_cast<const uint4*>(
                &Ag[row * HD + ((cw ^ (row & 7)) << 3)]);
            *reinterpret_cast<uint4*>(Xout + (long)r * HD + cw * 8) = v;
        }
    }
}

// ---------------------------------------------------------------------------
// Merged dual + decoder (64-row blocks, 3 LDS buffers) -- kept fused:
// unfusing would add a full x3 round-trip.
// ---------------------------------------------------------------------------
__global__ __launch_bounds__(256)
void k_dualdec(const unsigned short* __restrict__ Agg, const unsigned short* __restrict__ X,
               const unsigned short* __restrict__ WtL, const unsigned short* __restrict__ WtR,
               const float* __restrict__ bl_, const unsigned short* __restrict__ Wdec,
               const float* __restrict__ bdec, const unsigned short* __restrict__ Wfin,
               const float* __restrict__ bfin, float* __restrict__ Out, int n)
{
    __shared__ __align__(16) unsigned short Ag[64 * HD];
    __shared__ __align__(16) unsigned short Xs[64 * HD];
    __shared__ __align__(16) unsigned short Ts[64 * HD];

    const int tid  = threadIdx.x;
    const int lane = tid & 63, wave = tid >> 6;
    const int lr = lane & 15, lg = lane >> 4;
    const int row0 = blockIdx.x * 64;

#pragma unroll
    for (int it = 0; it < 4; ++it) {
        const int q   = wave * 4 + it;
        const int c   = q * 64 + lane;
        const int row = c >> 4, cw = c & 15;
        int grow = row0 + row; grow = grow < n ? grow : n - 1;
        const int gco = (cw ^ (row & 7)) << 3;
        __builtin_amdgcn_global_load_lds((const unsigned int*)(Agg + (long)grow * HD + gco),
                                         (unsigned int*)&Ag[q * 512], 16, 0, 0);
        __builtin_amdgcn_global_load_lds((const unsigned int*)(X + (long)grow * HD + gco),
                                         (unsigned int*)&Xs[q * 512], 16, 0, 0);
    }

    const int cb = wave * 32;
    short8 bl[2][4], br[2][4];
#pragma unroll
    for (int ct = 0; ct < 2; ++ct) {
        const unsigned short* pl = WtL + (long)(cb + ct * 16 + lr) * HD + lg * 8;
        const unsigned short* pr = WtR + (long)(cb + ct * 16 + lr) * HD + lg * 8;
#pragma unroll
        for (int kt = 0; kt < 4; ++kt) { bl[ct][kt] = ldg8(pl + kt * 32); br[ct][kt] = ldg8(pr + kt * 32); }
    }
    __syncthreads();   // (1)

    {
        f32x4 acc[4][2] = {};
#pragma unroll
        for (int kt = 0; kt < 4; ++kt) {
            short8 aa[4], ax[4];
#pragma unroll
            for (int rt = 0; rt < 4; ++rt) {
                const int base = (rt * 16 + lr) * HD + (((kt * 4 + lg) ^ (lr & 7)) << 3);
                aa[rt] = *reinterpret_cast<const short8*>(&Ag[base]);
                ax[rt] = *reinterpret_cast<const short8*>(&Xs[base]);
            }
#pragma unroll
            for (int rt = 0; rt < 4; ++rt)
#pragma unroll
                for (int ct = 0; ct < 2; ++ct) {
                    acc[rt][ct] = __builtin_amdgcn_mfma_f32_16x16x32_bf16(aa[rt], bl[ct][kt], acc[rt][ct], 0, 0, 0);
                    acc[rt][ct] = __builtin_amdgcn_mfma_f32_16x16x32_bf16(ax[rt], br[ct][kt], acc[rt][ct], 0, 0, 0);
                }
        }
        const float bv[2] = { bl_[cb + lr], bl_[cb + 16 + lr] };
#pragma unroll
        for (int rt = 0; rt < 4; ++rt)
#pragma unroll
            for (int ct = 0; ct < 2; ++ct) {
                const int cc = cb + ct * 16 + lr;
#pragma unroll
                for (int i = 0; i < 4; ++i) {
                    const int row = rt * 16 + lg * 4 + i;
                    const float v = fmaxf(acc[rt][ct][i] + bv[ct], 0.f);
                    Ts[row * HD + ((((cc >> 3) ^ (row & 7)) << 3) | (cc & 7))] = f2bf(v);
                }
            }
    }
    __syncthreads();   // (2)

    {
        short8 bd[2][4];
#pragma unroll
        for (int ct = 0; ct < 2; ++ct) {
            const unsigned short* bp = Wdec + (long)(cb + ct * 16 + lr) * HD + lg * 8;
#pragma unroll
            for (int kt = 0; kt < 4; ++kt) bd[ct][kt] = ldg8(bp + kt * 32);
        }
        f32x4 a2[4][2] = {};
#pragma unroll
        for (int kt = 0; kt < 4; ++kt) {
            short8 ah[4];
#pragma unroll
            for (int rt = 0; rt < 4; ++rt)
                ah[rt] = *reinterpret_cast<const short8*>(
                    &Ts[(rt * 16 + lr) * HD + (((kt * 4 + lg) ^ (lr & 7)) << 3)]);
#pragma unroll
            for (int rt = 0; rt < 4; ++rt)
#pragma unroll
                for (int ct = 0; ct < 2; ++ct)
                    a2[rt][ct] = __builtin_amdgcn_mfma_f32_16x16x32_bf16(ah[rt], bd[ct][kt], a2[rt][ct], 0, 0, 0);
        }
        const int cbf = wave * 16;
        short8 bfn[4];
#pragma unroll
        for (int kt = 0; kt < 4; ++kt)
            bfn[kt] = ldg8(Wfin + (long)(cbf + lr) * HD + lg * 8 + kt * 32);
        const float bv[2] = { bdec[cb + lr], bdec[cb + 16 + lr] };
#pragma unroll
        for (int rt = 0; rt < 4; ++rt)
#pragma unroll
            for (int ct = 0; ct < 2; ++ct) {
                const int cc = cb + ct * 16 + lr;
#pragma unroll
                for (int i = 0; i < 4; ++i) {
                    const int row = rt * 16 + lg * 4 + i;
                    const float v = fmaxf(a2[rt][ct][i] + bv[ct], 0.f);
                    Ag[row * HD + ((((cc >> 3) ^ (row & 7)) << 3) | (cc & 7))] = f2bf(v);
                }
            }
        __syncthreads();   // (3)

        f32x4 a3[4] = {};
#pragma unroll
        for (int kt = 0; kt < 4; ++kt) {
            short8 ah[4];
#pragma unroll
            for (int rt = 0; rt < 4; ++rt)
                ah[rt] = *reinterpret_cast<const short8*>(
                    &Ag[(rt * 16 + lr) * HD + (((kt * 4 + lg) ^ (lr & 7)) << 3)]);
#pragma unroll
            for (int rt = 0; rt < 4; ++rt)
                a3[rt] = __builtin_amdgcn_mfma_f32_16x16x32_bf16(ah[rt], bfn[kt], a3[rt], 0, 0, 0);
        }
        const float bvf = bfin[cbf + lr];
#pragma unroll
        for (int rt = 0; rt < 4; ++rt)
#pragma unroll
            for (int i = 0; i < 4; ++i) {
                const int r = row0 + rt * 16 + lg * 4 + i;
                if (r < n) Out[(long)r * 64 + cbf + lr] = a3[rt][i] + bvf;
            }
    }
}

// ---- scatter bodies (XCD-affine: 8 node-chunks, group = bid&7) ----
__device__ __forceinline__ void dev_deg(const int* __restrict__ dst, int* __restrict__ deg,
                                        int nE, int n, int bid, int nblk) {
    const int grp = bid & 7, bin = bid >> 3, nbin = nblk >> 3;
    const int chunk = (n + 7) >> 3;
    const int lo = grp * chunk, hi = min(n, lo + chunk);
    for (int e = bin * 256 + threadIdx.x; e < nE; e += nbin * 256) {
        const int d = dst[e];
        if (d >= lo && d < hi) atomicAdd(&deg[d], 1);
    }
}

// ---- fill: standalone, no LDS -> full occupancy for the atomic scatter ----
__global__ __launch_bounds__(256)
void k_fill(const int* __restrict__ src, const int* __restrict__ dst,
            const float* __restrict__ eattr, const int* __restrict__ rowstart,
            int* __restrict__ degcur, uint2* __restrict__ csr_rec, int nE, int n)
{
    const int bid = blockIdx.x, nblk = gridDim.x;
    const int grp = bid & 7, bin = bid >> 3, nbin = nblk >> 3;
    const int chunk = (n + 7) >> 3;
    const int lo = grp * chunk, hi = min(n, lo + chunk);
    for (int e = bin * 256 + threadIdx.x; e < nE; e += nbin * 256) {
        const int d = dst[e];
        if (d >= lo && d < hi) {
            const int p = rowstart[d] + atomicSub(&degcur[d], 1) - 1;
            uint2 rec;
            rec.x = (unsigned)src[e];
            rec.y = __builtin_bit_cast(unsigned, eattr[e]);
            csr_rec[p] = rec;
        }
    }
}

// ---- U1: deg ∪ cast(x->bf16) ∪ prep_w ----
__global__ __launch_bounds__(256)
void k_u1(const int* __restrict__ dst, int* __restrict__ deg, int nE,
          const float* __restrict__ xin, unsigned short* __restrict__ xb, long n8, int ncast,
          const float* __restrict__ Wlin, const float* __restrict__ Wmsg,
          const float* __restrict__ Wl,   const float* __restrict__ Wr,
          const float* __restrict__ Wdec, const float* __restrict__ Wfin,
          unsigned short* __restrict__ wt, int n)
{
    const int bid = blockIdx.x;
    if (bid < NBLK_SCAT) { dev_deg(dst, deg, nE, n, bid, NBLK_SCAT); return; }
    const int b = bid - NBLK_SCAT;
    if (b < ncast) {
        const long i = (long)b * 256 + threadIdx.x;
        if (i >= n8) return;
        const float4 v0 = *((const float4*)xin + i * 2);
        const float4 v1 = *((const float4*)xin + i * 2 + 1);
        unsigned o[4];
        o[0] = (unsigned)f2bf(v0.x) | ((unsigned)f2bf(v0.y) << 16);
        o[1] = (unsigned)f2bf(v0.z) | ((unsigned)f2bf(v0.w) << 16);
        o[2] = (unsigned)f2bf(v1.x) | ((unsigned)f2bf(v1.y) << 16);
        o[3] = (unsigned)f2bf(v1.z) | ((unsigned)f2bf(v1.w) << 16);
        *(uint4*)(xb + i * 8) = *(uint4*)o;
        return;
    }
    // prep_w: m: 0-2 W_lin, 3-5 W_msg(top 128), 6-8 W_l, 9-11 W_r, 12 W_dec, 13 W_fin(C=64)
    const int local = b - ncast;
    const int m = local >> 6;
    const float* src; int C = 128;
    if      (m < 3)  src = Wlin + m * 16384;
    else if (m < 6)  src = Wmsg + (m - 3) * (129 * 128);
    else if (m < 9)  src = Wl   + (m - 6) * 16384;
    else if (m < 12) src = Wr   + (m - 9) * 16384;
    else if (m == 12) src = Wdec;
    else { src = Wfin; C = 64; }
    const int elems = C * 128;
    const int e = (local & 63) * 256 + threadIdx.x;
    if (e >= elems) return;
    const int c = e >> 7, k = e & 127;
    wt[m * 16384 + e] = f2bf(src[k * C + c]);
}

// ---- U2: chunksum ∪ chain0 ----
__global__ __launch_bounds__(256)
void k_u2(const int* __restrict__ deg, int* __restrict__ csum, int nch,
          const unsigned short* __restrict__ A, const unsigned short* __restrict__ Wt1,
          const unsigned short* __restrict__ Wtc, const float* __restrict__ b1,
          const float* __restrict__ b2, unsigned short* __restrict__ Out, int n)
{
    __shared__ __align__(16) unsigned short As1[64 * HD];
    __shared__ __align__(16) unsigned short Hs [64 * HD];
    if ((int)blockIdx.x < nch) {
        __shared__ int s[256];
        const int t = threadIdx.x, i = blockIdx.x * 256 + t;
        s[t] = (i < n) ? deg[i] : 0;
        __syncthreads();
        for (int o = 128; o > 0; o >>= 1) { if (t < o) s[t] += s[t + o]; __syncthreads(); }
        if (t == 0) csum[blockIdx.x] = s[0];
        return;
    }
    dev_chain(As1, Hs, A, Wt1, Wtc, b1, b2, Out, n, blockIdx.x - nch);
}

// ---- scans ----
__global__ void k_scanmid(const int* __restrict__ csum, int* __restrict__ cbase,
                          int* __restrict__ rowstart, int nch, int n) {
    __shared__ int s[512];
    int t = threadIdx.x;
    int v = (t < nch) ? csum[t] : 0;
    s[t] = v; __syncthreads();
    for (int off = 1; off < 512; off <<= 1) {
        int tmp = (t >= off) ? s[t - off] : 0;
        __syncthreads();
        s[t] += tmp;
        __syncthreads();
    }
    if (t < nch) cbase[t] = s[t] - v;
    if (t == nch - 1) rowstart[n] = s[t];
}

__global__ void k_scan2(const int* __restrict__ deg, const int* __restrict__ cbase,
                        int* __restrict__ rowstart, float* __restrict__ inv_deg, int n) {
    __shared__ int s[256];
    int t = threadIdx.x, i = blockIdx.x * 256 + t;
    int v = (i < n) ? deg[i] : 0;
    s[t] = v; __syncthreads();
    for (int off = 1; off < 256; off <<= 1) {
        int tmp = (t >= off) ? s[t - off] : 0;
        __syncthreads();
        s[t] += tmp;
        __syncthreads();
    }
    if (i < n) {
        rowstart[i] = cbase[blockIdx.x] + s[t] - v;
        inv_deg[i] = 1.0f / fmaxf((float)v, 1.0f);
    }
}

// agg[i] = bf16( inv_deg[i] * sum_p relu(g[src_p] + attr_p * wlast) )
// 16 lanes/node, 16B/lane, 4-edge unroll.
__global__ __launch_bounds__(256)
void k_agg(const unsigned short* __restrict__ g, const uint2* __restrict__ rec,
           const int* __restrict__ rs, const float* __restrict__ inv_deg,
           const float* __restrict__ wlast, unsigned short* __restrict__ agg, int n) {
    const int lane = threadIdx.x & 15;
    const int node = blockIdx.x * 16 + (threadIdx.x >> 4);
    if (node >= n) return;
    const int c0 = lane * 8;
    const float4 wla = *(const float4*)(wlast + c0);
    const float4 wlb = *(const float4*)(wlast + c0 + 4);
    const int p0 = rs[node], p1 = rs[node + 1];
    float a0=0,a1=0,a2=0,a3=0,a4=0,a5=0,a6=0,a7=0;
    int p = p0;
    for (; p + 4 <= p1; p += 4) {
        uint2 r[4];
#pragma unroll
        for (int u = 0; u < 4; ++u) r[u] = rec[p + u];
        uint4 G[4];
#pragma unroll
        for (int u = 0; u < 4; ++u) G[u] = *(const uint4*)(g + (long)r[u].x * HD + c0);
#pragma unroll
        for (int u = 0; u < 4; ++u) {
            const float e = __builtin_bit_cast(float, r[u].y);
            a0 += fmaxf(fmaf(e, wla.x, bflo(G[u].x)), 0.f);
            a1 += fmaxf(fmaf(e, wla.y, bfhi(G[u].x)), 0.f);
            a2 += fmaxf(fmaf(e, wla.z, bflo(G[u].y)), 0.f);
            a3 += fmaxf(fmaf(e, wla.w, bfhi(G[u].y)), 0.f);
            a4 += fmaxf(fmaf(e, wlb.x, bflo(G[u].z)), 0.f);
            a5 += fmaxf(fmaf(e, wlb.y, bfhi(G[u].z)), 0.f);
            a6 += fmaxf(fmaf(e, wlb.z, bflo(G[u].w)), 0.f);
            a7 += fmaxf(fmaf(e, wlb.w, bfhi(G[u].w)), 0.f);
        }
    }
    for (; p < p1; ++p) {
        const uint2 r0 = rec[p];
        const float e0 = __builtin_bit_cast(float, r0.y);
        const uint4 G0 = *(const uint4*)(g + (long)r0.x * HD + c0);
        a0 += fmaxf(fmaf(e0, wla.x, bflo(G0.x)), 0.f);
        a1 += fmaxf(fmaf(e0, wla.y, bfhi(G0.x)), 0.f);
        a2 += fmaxf(fmaf(e0, wla.z, bflo(G0.y)), 0.f);
        a3 += fmaxf(fmaf(e0, wla.w, bfhi(G0.y)), 0.f);
        a4 += fmaxf(fmaf(e0, wlb.x, bflo(G0.z)), 0.f);
        a5 += fmaxf(fmaf(e0, wlb.y, bfhi(G0.z)), 0.f);
        a6 += fmaxf(fmaf(e0, wlb.z, bflo(G0.w)), 0.f);
        a7 += fmaxf(fmaf(e0, wlb.w, bfhi(G0.w)), 0.f);
    }
    const float id = inv_deg[node];
    uint4 o;
    o.x = (unsigned)f2bf(a0 * id) | ((unsigned)f2bf(a1 * id) << 16);
    o.y = (unsigned)f2bf(a2 * id) | ((unsigned)f2bf(a3 * id) << 16);
    o.z = (unsigned)f2bf(a4 * id) | ((unsigned)f2bf(a5 * id) << 16);
    o.w = (unsigned)f2bf(a6 * id) | ((unsigned)f2bf(a7 * id) << 16);
    *(uint4*)(agg + (long)node * HD + c0) = o;
}

extern "C" void kernel_launch(void* const* d_in, const int* in_sizes, int n_in,
                              void* d_out, int out_size, void* d_ws, size_t ws_size,
                              hipStream_t stream)
{
    const float* x     = (const float*)d_in[0];
    const float* eattr = (const float*)d_in[1];
    const float* W_lin = (const float*)d_in[2];
    const float* b_lin = (const float*)d_in[3];
    const float* W_msg = (const float*)d_in[4];
    const float* b_msg = (const float*)d_in[5];
    const float* W_l   = (const float*)d_in[6];
    const float* b_l   = (const float*)d_in[7];
    const float* W_r   = (const float*)d_in[8];
    const float* W_dec = (const float*)d_in[9];
    const float* b_dec = (const float*)d_in[10];
    const float* W_fin = (const float*)d_in[11];
    const float* b_fin = (const float*)d_in[12];
    const int*   ei    = (const int*)d_in[13];

    const int N = in_sizes[0] / HD;   // 100000
    const int E = in_sizes[1];        // 600000
    const int* srcv = ei;
    const int* dstv = ei + E;

    char* wsb = (char*)d_ws;
    size_t off = 0;
    auto carve = [&](size_t bytes) -> void* {
        void* p = wsb + off;
        off += (bytes + 255) & ~(size_t)255;
        return p;
    };
    unsigned short* xb = (unsigned short*)carve((size_t)N * HD * 2);
    unsigned short* t1 = (unsigned short*)carve((size_t)N * HD * 2);
    unsigned short* t2 = (unsigned short*)carve((size_t)N * HD * 2);
    unsigned short* t3 = (unsigned short*)carve((size_t)N * HD * 2);
    unsigned short* wt = (unsigned short*)carve((size_t)14 * 16384 * 2);
    uint2* csr_rec  = (uint2*)carve((size_t)E * 8);
    int*   rowstart = (int*)carve((size_t)(N + 1) * 4);
    int*   deg      = (int*)carve((size_t)N * 4);
    float* inv_deg  = (float*)carve((size_t)N * 4);
    const int NCH = (N + 255) / 256;
    int* csum  = (int*)carve((size_t)NCH * 4);
    int* cbase = (int*)carve((size_t)NCH * 4);

    if (off > ws_size) {
        hipMemsetAsync(d_out, 0, (size_t)out_size * 4, stream);
        return;
    }

    hipMemsetAsync(deg, 0, (size_t)N * 4, stream);

    auto WT = [&](int m) { return wt + (size_t)m * 16384; };
    const int NB64 = (N + 63) / 64;
    const int GAGG = (N + 15) / 16;
    const long n8 = (long)N * HD / 8;
    const int ncast = (int)((n8 + 255) / 256);

    // U1: deg (4096 scatter blocks) ∪ cast ∪ prep_w
    k_u1<<<NBLK_SCAT + ncast + 14 * 64, 256, 0, stream>>>(
        dstv, deg, E, x, xb, n8, ncast, W_lin, W_msg, W_l, W_r, W_dec, W_fin, wt, N);
    // U2: chunksum ∪ chain0 (xb -> g0 in t2)
    k_u2<<<NCH + NB64, 256, 0, stream>>>(
        deg, csum, NCH, xb, WT(0), WT(3), b_lin, b_msg, t2, N);
    k_scanmid<<<1, 512, 0, stream>>>(csum, cbase, rowstart, NCH, N);
    k_scan2<<<NCH, 256, 0, stream>>>(deg, cbase, rowstart, inv_deg, N);
    // fill: standalone, LDS-free, 4096 blocks
    k_fill<<<NBLK_SCAT, 256, 0, stream>>>(srcv, dstv, eattr, rowstart, deg, csr_rec, E, N);

    auto wlast = [&](int l) { return W_msg + (size_t)l * (HD + 1) * HD + (size_t)HD * HD; };

    // Alias-free rotation: x path xb -> t3 -> xb ; g -> t2 ; agg -> t1.
    // agg0: g0(t2) -> t1
    k_agg<<<GAGG, 256, 0, stream>>>(t2, csr_rec, rowstart, inv_deg, wlast(0), t1, N);
    // dual0: x1 = relu(t1@Wl0 + xb@Wr0 + bl0) -> t3
    k_dual<<<NB64, 256, 0, stream>>>(t1, xb, WT(6), WT(9), b_l, t3, N);
    // chain1: g1 = relu(t3@Wlin1)@Wmsg1 -> t2 (g0 dead)
    k_chain<<<NB64, 256, 0, stream>>>(t3, WT(1), WT(4), b_lin + HD, b_msg + HD, t2, N);
    // agg1: g1(t2) -> t1
    k_agg<<<GAGG, 256, 0, stream>>>(t2, csr_rec, rowstart, inv_deg, wlast(1), t1, N);
    // dual1: x2 = relu(t1@Wl1 + t3@Wr1 + bl1) -> xb (x0 dead)
    k_dual<<<NB64, 256, 0, stream>>>(t1, t3, WT(7), WT(10), b_l + HD, xb, N);
    // chain2: g2 = relu(xb@Wlin2)@Wmsg2 -> t2 (g1 dead)
    k_chain<<<NB64, 256, 0, stream>>>(xb, WT(2), WT(5), b_lin + 2 * HD, b_msg + 2 * HD, t2, N);
    // agg2: g2(t2) -> t1
    k_agg<<<GAGG, 256, 0, stream>>>(t2, csr_rec, rowstart, inv_deg, wlast(2), t1, N);
    // dual2 + decoder: Agg=t1, X=xb -> d_out
    k_dualdec<<<NB64, 256, 0, stream>>>(t1, xb, WT(8), WT(11), b_l + 2 * HD,
                                        WT(12), b_dec, WT(13), b_fin, (float*)d_out, N);
}

// Round 20
// 297.361 us; speedup vs baseline: 1.0432x; 1.0432x over previous
//
#include <hip/hip_runtime.h>

using short8 = __attribute__((ext_vector_type(8))) short;
using f32x4  = __attribute__((ext_vector_type(4))) float;

constexpr int HD = 128;
constexpr int NBLK_SCAT = 4096;   // scatter (deg/fill) blocks: 8 XCD groups x 512

__device__ __forceinline__ unsigned short f2bf(float f) {
    unsigned u = __builtin_bit_cast(unsigned, f);
    u += 0x7fffu + ((u >> 16) & 1u);          // round-to-nearest-even
    return (unsigned short)(u >> 16);
}
__device__ __forceinline__ float bflo(unsigned u) { return __builtin_bit_cast(float, u << 16); }
__device__ __forceinline__ float bfhi(unsigned u) { return __builtin_bit_cast(float, u & 0xffff0000u); }

__device__ __forceinline__ short8 ldg8(const unsigned short* p) {
    return *reinterpret_cast<const short8*>(p);   // 16B contiguous, aligned
}

// ---------------------------------------------------------------------------
// Chain GEMM body: Out = (relu(A @ Wt1 + b1)) @ Wtc + b2. 64 rows x 128 cols.
// Output staged into As1 (dead after phase 1), coalesced uint4 write-out.
// ---------------------------------------------------------------------------
__device__ __forceinline__ void dev_chain(unsigned short* As1, unsigned short* Hs,
    const unsigned short* __restrict__ A, const unsigned short* __restrict__ Wt1,
    const unsigned short* __restrict__ Wtc, const float* __restrict__ b1,
    const float* __restrict__ b2, unsigned short* __restrict__ Out, int nrows, int bid)
{
    const int tid  = threadIdx.x;
    const int lane = tid & 63, wave = tid >> 6;
    const int lr = lane & 15, lg = lane >> 4;
    const int row0 = bid * 64;

#pragma unroll
    for (int it = 0; it < 4; ++it) {
        const int q   = wave * 4 + it;
        const int c   = q * 64 + lane;
        const int row = c >> 4, cw = c & 15;
        int grow = row0 + row; grow = grow < nrows ? grow : nrows - 1;
        const int gco = (cw ^ (row & 7)) << 3;
        __builtin_amdgcn_global_load_lds((const unsigned int*)(A + (long)grow * HD + gco),
                                         (unsigned int*)&As1[q * 512], 16, 0, 0);
    }

    const int cb = wave * 32;
    short8 bf1[2][4];
#pragma unroll
    for (int ct = 0; ct < 2; ++ct) {
        const unsigned short* bp = Wt1 + (long)(cb + ct * 16 + lr) * HD + lg * 8;
#pragma unroll
        for (int kt = 0; kt < 4; ++kt) bf1[ct][kt] = ldg8(bp + kt * 32);
    }
    short8 bfc[2][4];
#pragma unroll
    for (int ct = 0; ct < 2; ++ct) {
        const unsigned short* bp = Wtc + (long)(cb + ct * 16 + lr) * HD + lg * 8;
#pragma unroll
        for (int kt = 0; kt < 4; ++kt) bfc[ct][kt] = ldg8(bp + kt * 32);
    }

    __syncthreads();   // (1) DMA + weights drained

    f32x4 acc[4][2] = {};
#pragma unroll
    for (int kt = 0; kt < 4; ++kt) {
        short8 af[4];
#pragma unroll
        for (int rt = 0; rt < 4; ++rt)
            af[rt] = *reinterpret_cast<const short8*>(
                &As1[(rt * 16 + lr) * HD + (((kt * 4 + lg) ^ (lr & 7)) << 3)]);
#pragma unroll
        for (int rt = 0; rt < 4; ++rt)
#pragma unroll
            for (int ct = 0; ct < 2; ++ct)
                acc[rt][ct] = __builtin_amdgcn_mfma_f32_16x16x32_bf16(af[rt], bf1[ct][kt], acc[rt][ct], 0, 0, 0);
    }

    const float bv1[2] = { b1[cb + lr], b1[cb + 16 + lr] };
#pragma unroll
    for (int rt = 0; rt < 4; ++rt)
#pragma unroll
        for (int ct = 0; ct < 2; ++ct) {
            const int cc = cb + ct * 16 + lr;
#pragma unroll
            for (int i = 0; i < 4; ++i) {
                const int row = rt * 16 + lg * 4 + i;
                const float v = fmaxf(acc[rt][ct][i] + bv1[ct], 0.f);
                Hs[row * HD + ((((cc >> 3) ^ (row & 7)) << 3) | (cc & 7))] = f2bf(v);
            }
        }
    __syncthreads();   // (2) h visible; As1 reads all done

    f32x4 acc2[4][2] = {};
#pragma unroll
    for (int kt = 0; kt < 4; ++kt) {
        short8 ah[4];
#pragma unroll
        for (int rt = 0; rt < 4; ++rt)
            ah[rt] = *reinterpret_cast<const short8*>(
                &Hs[(rt * 16 + lr) * HD + (((kt * 4 + lg) ^ (lr & 7)) << 3)]);
#pragma unroll
        for (int rt = 0; rt < 4; ++rt)
#pragma unroll
            for (int ct = 0; ct < 2; ++ct)
                acc2[rt][ct] = __builtin_amdgcn_mfma_f32_16x16x32_bf16(ah[rt], bfc[ct][kt], acc2[rt][ct], 0, 0, 0);
    }
    const float bv2[2] = { b2[cb + lr], b2[cb + 16 + lr] };
#pragma unroll
    for (int rt = 0; rt < 4; ++rt)
#pragma unroll
        for (int ct = 0; ct < 2; ++ct) {
            const int cc = cb + ct * 16 + lr;
#pragma unroll
            for (int i = 0; i < 4; ++i) {
                const int row = rt * 16 + lg * 4 + i;
                As1[row * HD + ((((cc >> 3) ^ (row & 7)) << 3) | (cc & 7))] = f2bf(acc2[rt][ct][i] + bv2[ct]);
            }
        }
    __syncthreads();   // (3) staged output visible

#pragma unroll
    for (int k = 0; k < 4; ++k) {
        const int c   = tid + k * 256;
        const int row = c >> 4, cw = c & 15;
        const int r = row0 + row;
        if (r < nrows) {
            const uint4 v = *reinterpret_cast<const uint4*>(
                &As1[row * HD + ((cw ^ (row & 7)) << 3)]);
            *reinterpret_cast<uint4*>(Out + (long)r * HD + cw * 8) = v;
        }
    }
}

// ---------------------------------------------------------------------------
// Merged dual + next-layer chain (64-row blocks, 3 LDS buffers = 48KB):
//   phase1: x' = relu(Ag@WtL + Xs@WtR + bl) -> Ts (LDS only)
//   phase2: h  = relu(Ts@Wt1 + b1) -> Ag
//   phase3: g  = Ag@Wtc + b2 -> Xs (dead since barrier 2)
//   tail : merged coalesced uint4 write-out Ts->Xout, Xs->Gout
// Caller guarantees Xout/Gout do not alias Agg/X.
// ---------------------------------------------------------------------------
__global__ __launch_bounds__(256)
void k_dualchain(const unsigned short* __restrict__ Agg, const unsigned short* __restrict__ X,
                 const unsigned short* __restrict__ WtL, const unsigned short* __restrict__ WtR,
                 const float* __restrict__ bl_,
                 const unsigned short* __restrict__ Wt1, const float* __restrict__ b1,
                 const unsigned short* __restrict__ Wtc, const float* __restrict__ b2,
                 unsigned short* __restrict__ Xout, unsigned short* __restrict__ Gout, int n)
{
    __shared__ __align__(16) unsigned short Ag[64 * HD];
    __shared__ __align__(16) unsigned short Xs[64 * HD];
    __shared__ __align__(16) unsigned short Ts[64 * HD];

    const int tid  = threadIdx.x;
    const int lane = tid & 63, wave = tid >> 6;
    const int lr = lane & 15, lg = lane >> 4;
    const int row0 = blockIdx.x * 64;

#pragma unroll
    for (int it = 0; it < 4; ++it) {
        const int q   = wave * 4 + it;
        const int c   = q * 64 + lane;
        const int row = c >> 4, cw = c & 15;
        int grow = row0 + row; grow = grow < n ? grow : n - 1;
        const int gco = (cw ^ (row & 7)) << 3;
        __builtin_amdgcn_global_load_lds((const unsigned int*)(Agg + (long)grow * HD + gco),
                                         (unsigned int*)&Ag[q * 512], 16, 0, 0);
        __builtin_amdgcn_global_load_lds((const unsigned int*)(X + (long)grow * HD + gco),
                                         (unsigned int*)&Xs[q * 512], 16, 0, 0);
    }

    const int cb = wave * 32;
    short8 bl[2][4], br[2][4];
#pragma unroll
    for (int ct = 0; ct < 2; ++ct) {
        const unsigned short* pl = WtL + (long)(cb + ct * 16 + lr) * HD + lg * 8;
        const unsigned short* pr = WtR + (long)(cb + ct * 16 + lr) * HD + lg * 8;
#pragma unroll
        for (int kt = 0; kt < 4; ++kt) { bl[ct][kt] = ldg8(pl + kt * 32); br[ct][kt] = ldg8(pr + kt * 32); }
    }
    __syncthreads();   // (1) DMA + weights drained

    // phase 1: x' = relu(Ag@WtL + Xs@WtR + bl) -> Ts (LDS only)
    {
        f32x4 acc[4][2] = {};
#pragma unroll
        for (int kt = 0; kt < 4; ++kt) {
            short8 aa[4], ax[4];
#pragma unroll
            for (int rt = 0; rt < 4; ++rt) {
                const int base = (rt * 16 + lr) * HD + (((kt * 4 + lg) ^ (lr & 7)) << 3);
                aa[rt] = *reinterpret_cast<const short8*>(&Ag[base]);
                ax[rt] = *reinterpret_cast<const short8*>(&Xs[base]);
            }
#pragma unroll
            for (int rt = 0; rt < 4; ++rt)
#pragma unroll
                for (int ct = 0; ct < 2; ++ct) {
                    acc[rt][ct] = __builtin_amdgcn_mfma_f32_16x16x32_bf16(aa[rt], bl[ct][kt], acc[rt][ct], 0, 0, 0);
                    acc[rt][ct] = __builtin_amdgcn_mfma_f32_16x16x32_bf16(ax[rt], br[ct][kt], acc[rt][ct], 0, 0, 0);
                }
        }
        const float bv[2] = { bl_[cb + lr], bl_[cb + 16 + lr] };
#pragma unroll
        for (int rt = 0; rt < 4; ++rt)
#pragma unroll
            for (int ct = 0; ct < 2; ++ct) {
                const int cc = cb + ct * 16 + lr;
#pragma unroll
                for (int i = 0; i < 4; ++i) {
                    const int row = rt * 16 + lg * 4 + i;
                    const float v = fmaxf(acc[rt][ct][i] + bv[ct], 0.f);
                    Ts[row * HD + ((((cc >> 3) ^ (row & 7)) << 3) | (cc & 7))] = f2bf(v);
                }
            }
    }
    __syncthreads();   // (2) Ts visible; all Ag/Xs reads done

    // phase 2: h = relu(Ts@Wt1 + b1) -> Ag
    {
        short8 b1f[2][4];
#pragma unroll
        for (int ct = 0; ct < 2; ++ct) {
            const unsigned short* bp = Wt1 + (long)(cb + ct * 16 + lr) * HD + lg * 8;
#pragma unroll
            for (int kt = 0; kt < 4; ++kt) b1f[ct][kt] = ldg8(bp + kt * 32);
        }
        f32x4 a2[4][2] = {};
#pragma unroll
        for (int kt = 0; kt < 4; ++kt) {
            short8 ah[4];
#pragma unroll
            for (int rt = 0; rt < 4; ++rt)
                ah[rt] = *reinterpret_cast<const short8*>(
                    &Ts[(rt * 16 + lr) * HD + (((kt * 4 + lg) ^ (lr & 7)) << 3)]);
#pragma unroll
            for (int rt = 0; rt < 4; ++rt)
#pragma unroll
                for (int ct = 0; ct < 2; ++ct)
                    a2[rt][ct] = __builtin_amdgcn_mfma_f32_16x16x32_bf16(ah[rt], b1f[ct][kt], a2[rt][ct], 0, 0, 0);
        }
        short8 bcf[2][4];
#pragma unroll
        for (int ct = 0; ct < 2; ++ct) {
            const unsigned short* bp = Wtc + (long)(cb + ct * 16 + lr) * HD + lg * 8;
#pragma unroll
            for (int kt = 0; kt < 4; ++kt) bcf[ct][kt] = ldg8(bp + kt * 32);
        }
        const float bv[2] = { b1[cb + lr], b1[cb + 16 + lr] };
#pragma unroll
        for (int rt = 0; rt < 4; ++rt)
#pragma unroll
            for (int ct = 0; ct < 2; ++ct) {
                const int cc = cb + ct * 16 + lr;
#pragma unroll
                for (int i = 0; i < 4; ++i) {
                    const int row = rt * 16 + lg * 4 + i;
                    const float v = fmaxf(a2[rt][ct][i] + bv[ct], 0.f);
                    Ag[row * HD + ((((cc >> 3) ^ (row & 7)) << 3) | (cc & 7))] = f2bf(v);
                }
            }
        __syncthreads();   // (3) h visible

        // phase 3: g = Ag@Wtc + b2 -> Xs (dead since barrier 2)
        f32x4 a3[4][2] = {};
#pragma unroll
        for (int kt = 0; kt < 4; ++kt) {
            short8 ah[4];
#pragma unroll
            for (int rt = 0; rt < 4; ++rt)
                ah[rt] = *reinterpret_cast<const short8*>(
                    &Ag[(rt * 16 + lr) * HD + (((kt * 4 + lg) ^ (lr & 7)) << 3)]);
#pragma unroll
            for (int rt = 0; rt < 4; ++rt)
#pragma unroll
                for (int ct = 0; ct < 2; ++ct)
                    a3[rt][ct] = __builtin_amdgcn_mfma_f32_16x16x32_bf16(ah[rt], bcf[ct][kt], a3[rt][ct], 0, 0, 0);
        }
        const float bv2[2] = { b2[cb + lr], b2[cb + 16 + lr] };
#pragma unroll
        for (int rt = 0; rt < 4; ++rt)
#pragma unroll
            for (int ct = 0; ct < 2; ++ct) {
                const int cc = cb + ct * 16 + lr;
#pragma unroll
                for (int i = 0; i < 4; ++i) {
                    const int row = rt * 16 + lg * 4 + i;
                    Xs[row * HD + ((((cc >> 3) ^ (row & 7)) << 3) | (cc & 7))] = f2bf(a3[rt][ct][i] + bv2[ct]);
                }
            }
    }
    __syncthreads();   // (4) staged outputs visible

    // merged coalesced write-out: Ts -> Xout (x'), Xs -> Gout (g)
#pragma unroll
    for (int k = 0; k < 4; ++k) {
        const int c   = tid + k * 256;
        const int row = c >> 4, cw = c & 15;
        const int r = row0 + row;
        if (r < n) {
            const int off = row * HD + ((cw ^ (row & 7)) << 3);
            *reinterpret_cast<uint4*>(Xout + (long)r * HD + cw * 8) =
                *reinterpret_cast<const uint4*>(&Ts[off]);
            *reinterpret_cast<uint4*>(Gout + (long)r * HD + cw * 8) =
                *reinterpret_cast<const uint4*>(&Xs[off]);
        }
    }
}

// ---------------------------------------------------------------------------
// Merged dual + decoder (64-row blocks, 3 LDS buffers):
//   phase1: x3 = relu(Ag@WtL + Xs@WtR + bl) -> Ts
//   phase2: emb = relu(Ts@Wdec + bdec) -> Ag
//   phase3: logits -> f32 staged into Ts (dead after barrier 3; 64x64 f32 =
//           16KB = Ts size), swizzled col^((row&3)<<4); then coalesced float4.
// ---------------------------------------------------------------------------
__global__ __launch_bounds__(256)
void k_dualdec(const unsigned short* __restrict__ Agg, const unsigned short* __restrict__ X,
               const unsigned short* __restrict__ WtL, const unsigned short* __restrict__ WtR,
               const float* __restrict__ bl_, const unsigned short* __restrict__ Wdec,
               const float* __restrict__ bdec, const unsigned short* __restrict__ Wfin,
               const float* __restrict__ bfin, float* __restrict__ Out, int n)
{
    __shared__ __align__(16) unsigned short Ag[64 * HD];
    __shared__ __align__(16) unsigned short Xs[64 * HD];
    __shared__ __align__(16) unsigned short Ts[64 * HD];

    const int tid  = threadIdx.x;
    const int lane = tid & 63, wave = tid >> 6;
    const int lr = lane & 15, lg = lane >> 4;
    const int row0 = blockIdx.x * 64;

#pragma unroll
    for (int it = 0; it < 4; ++it) {
        const int q   = wave * 4 + it;
        const int c   = q * 64 + lane;
        const int row = c >> 4, cw = c & 15;
        int grow = row0 + row; grow = grow < n ? grow : n - 1;
        const int gco = (cw ^ (row & 7)) << 3;
        __builtin_amdgcn_global_load_lds((const unsigned int*)(Agg + (long)grow * HD + gco),
                                         (unsigned int*)&Ag[q * 512], 16, 0, 0);
        __builtin_amdgcn_global_load_lds((const unsigned int*)(X + (long)grow * HD + gco),
                                         (unsigned int*)&Xs[q * 512], 16, 0, 0);
    }

    const int cb = wave * 32;
    short8 bl[2][4], br[2][4];
#pragma unroll
    for (int ct = 0; ct < 2; ++ct) {
        const unsigned short* pl = WtL + (long)(cb + ct * 16 + lr) * HD + lg * 8;
        const unsigned short* pr = WtR + (long)(cb + ct * 16 + lr) * HD + lg * 8;
#pragma unroll
        for (int kt = 0; kt < 4; ++kt) { bl[ct][kt] = ldg8(pl + kt * 32); br[ct][kt] = ldg8(pr + kt * 32); }
    }
    __syncthreads();   // (1)

    // phase 1: x3 = relu(Ag@WtL + Xs@WtR + bl) -> Ts
    {
        f32x4 acc[4][2] = {};
#pragma unroll
        for (int kt = 0; kt < 4; ++kt) {
            short8 aa[4], ax[4];
#pragma unroll
            for (int rt = 0; rt < 4; ++rt) {
                const int base = (rt * 16 + lr) * HD + (((kt * 4 + lg) ^ (lr & 7)) << 3);
                aa[rt] = *reinterpret_cast<const short8*>(&Ag[base]);
                ax[rt] = *reinterpret_cast<const short8*>(&Xs[base]);
            }
#pragma unroll
            for (int rt = 0; rt < 4; ++rt)
#pragma unroll
                for (int ct = 0; ct < 2; ++ct) {
                    acc[rt][ct] = __builtin_amdgcn_mfma_f32_16x16x32_bf16(aa[rt], bl[ct][kt], acc[rt][ct], 0, 0, 0);
                    acc[rt][ct] = __builtin_amdgcn_mfma_f32_16x16x32_bf16(ax[rt], br[ct][kt], acc[rt][ct], 0, 0, 0);
                }
        }
        const float bv[2] = { bl_[cb + lr], bl_[cb + 16 + lr] };
#pragma unroll
        for (int rt = 0; rt < 4; ++rt)
#pragma unroll
            for (int ct = 0; ct < 2; ++ct) {
                const int cc = cb + ct * 16 + lr;
#pragma unroll
                for (int i = 0; i < 4; ++i) {
                    const int row = rt * 16 + lg * 4 + i;
                    const float v = fmaxf(acc[rt][ct][i] + bv[ct], 0.f);
                    Ts[row * HD + ((((cc >> 3) ^ (row & 7)) << 3) | (cc & 7))] = f2bf(v);
                }
            }
    }
    __syncthreads();   // (2)

    // phase 2: emb = relu(Ts@Wdec + bdec) -> Ag
    {
        short8 bd[2][4];
#pragma unroll
        for (int ct = 0; ct < 2; ++ct) {
            const unsigned short* bp = Wdec + (long)(cb + ct * 16 + lr) * HD + lg * 8;
#pragma unroll
            for (int kt = 0; kt < 4; ++kt) bd[ct][kt] = ldg8(bp + kt * 32);
        }
        f32x4 a2[4][2] = {};
#pragma unroll
        for (int kt = 0; kt < 4; ++kt) {
            short8 ah[4];
#pragma unroll
            for (int rt = 0; rt < 4; ++rt)
                ah[rt] = *reinterpret_cast<const short8*>(
                    &Ts[(rt * 16 + lr) * HD + (((kt * 4 + lg) ^ (lr & 7)) << 3)]);
#pragma unroll
            for (int rt = 0; rt < 4; ++rt)
#pragma unroll
                for (int ct = 0; ct < 2; ++ct)
                    a2[rt][ct] = __builtin_amdgcn_mfma_f32_16x16x32_bf16(ah[rt], bd[ct][kt], a2[rt][ct], 0, 0, 0);
        }
        const int cbf = wave * 16;
        short8 bfn[4];
#pragma unroll
        for (int kt = 0; kt < 4; ++kt)
            bfn[kt] = ldg8(Wfin + (long)(cbf + lr) * HD + lg * 8 + kt * 32);
        const float bv[2] = { bdec[cb + lr], bdec[cb + 16 + lr] };
#pragma unroll
        for (int rt = 0; rt < 4; ++rt)
#pragma unroll
            for (int ct = 0; ct < 2; ++ct) {
                const int cc = cb + ct * 16 + lr;
#pragma unroll
                for (int i = 0; i < 4; ++i) {
                    const int row = rt * 16 + lg * 4 + i;
                    const float v = fmaxf(a2[rt][ct][i] + bv[ct], 0.f);
                    Ag[row * HD + ((((cc >> 3) ^ (row & 7)) << 3) | (cc & 7))] = f2bf(v);
                }
            }
        __syncthreads();   // (3) emb visible; Ts reads all done

        // phase 3: logits = Ag@Wfin + bfin -> staged f32 in Ts (reused)
        float* Tf = reinterpret_cast<float*>(Ts);
        f32x4 a3[4] = {};
#pragma unroll
        for (int kt = 0; kt < 4; ++kt) {
            short8 ah[4];
#pragma unroll
            for (int rt = 0; rt < 4; ++rt)
                ah[rt] = *reinterpret_cast<const short8*>(
                    &Ag[(rt * 16 + lr) * HD + (((kt * 4 + lg) ^ (lr & 7)) << 3)]);
#pragma unroll
            for (int rt = 0; rt < 4; ++rt)
                a3[rt] = __builtin_amdgcn_mfma_f32_16x16x32_bf16(ah[rt], bfn[kt], a3[rt], 0, 0, 0);
        }
        const float bvf = bfin[cbf + lr];
        const int col = cbf + lr;
#pragma unroll
        for (int rt = 0; rt < 4; ++rt)
#pragma unroll
            for (int i = 0; i < 4; ++i) {
                const int row = rt * 16 + lg * 4 + i;
                Tf[row * 64 + (col ^ ((row & 3) << 4))] = a3[rt][i] + bvf;
            }
    }
    __syncthreads();   // (4) staged logits visible

    // coalesced float4 write-out: 64 rows x 16 float4-chunks
    {
        const float* Tf = reinterpret_cast<const float*>(Ts);
#pragma unroll
        for (int k = 0; k < 4; ++k) {
            const int c   = tid + k * 256;
            const int row = c >> 4, cw = c & 15;
            const int r = row0 + row;
            if (r < n) {
                const float4 v = *reinterpret_cast<const float4*>(
                    &Tf[row * 64 + ((cw << 2) ^ ((row & 3) << 4))]);
                *reinterpret_cast<float4*>(Out + (long)r * 64 + cw * 4) = v;
            }
        }
    }
}

// ---- scatter bodies (XCD-affine: 8 node-chunks, group = bid&7) ----
__device__ __forceinline__ void dev_deg(const int* __restrict__ dst, int* __restrict__ deg,
                                        int nE, int n, int bid, int nblk) {
    const int grp = bid & 7, bin = bid >> 3, nbin = nblk >> 3;
    const int chunk = (n + 7) >> 3;
    const int lo = grp * chunk, hi = min(n, lo + chunk);
    for (int e = bin * 256 + threadIdx.x; e < nE; e += nbin * 256) {
        const int d = dst[e];
        if (d >= lo && d < hi) atomicAdd(&deg[d], 1);
    }
}

// ---- fill: standalone, no LDS -> full occupancy for the atomic scatter ----
__global__ __launch_bounds__(256)
void k_fill(const int* __restrict__ src, const int* __restrict__ dst,
            const float* __restrict__ eattr, const int* __restrict__ rowstart,
            int* __restrict__ degcur, uint2* __restrict__ csr_rec, int nE, int n)
{
    const int bid = blockIdx.x, nblk = gridDim.x;
    const int grp = bid & 7, bin = bid >> 3, nbin = nblk >> 3;
    const int chunk = (n + 7) >> 3;
    const int lo = grp * chunk, hi = min(n, lo + chunk);
    for (int e = bin * 256 + threadIdx.x; e < nE; e += nbin * 256) {
        const int d = dst[e];
        if (d >= lo && d < hi) {
            const int p = rowstart[d] + atomicSub(&degcur[d], 1) - 1;
            uint2 rec;
            rec.x = (unsigned)src[e];
            rec.y = __builtin_bit_cast(unsigned, eattr[e]);
            csr_rec[p] = rec;
        }
    }
}

// ---- U1: deg ∪ cast(x->bf16) ∪ prep_w ----
__global__ __launch_bounds__(256)
void k_u1(const int* __restrict__ dst, int* __restrict__ deg, int nE,
          const float* __restrict__ xin, unsigned short* __restrict__ xb, long n8, int ncast,
          const float* __restrict__ Wlin, const float* __restrict__ Wmsg,
          const float* __restrict__ Wl,   const float* __restrict__ Wr,
          const float* __restrict__ Wdec, const float* __restrict__ Wfin,
          unsigned short* __restrict__ wt, int n)
{
    const int bid = blockIdx.x;
    if (bid < NBLK_SCAT) { dev_deg(dst, deg, nE, n, bid, NBLK_SCAT); return; }
    const int b = bid - NBLK_SCAT;
    if (b < ncast) {
        const long i = (long)b * 256 + threadIdx.x;
        if (i >= n8) return;
        const float4 v0 = *((const float4*)xin + i * 2);
        const float4 v1 = *((const float4*)xin + i * 2 + 1);
        unsigned o[4];
        o[0] = (unsigned)f2bf(v0.x) | ((unsigned)f2bf(v0.y) << 16);
        o[1] = (unsigned)f2bf(v0.z) | ((unsigned)f2bf(v0.w) << 16);
        o[2] = (unsigned)f2bf(v1.x) | ((unsigned)f2bf(v1.y) << 16);
        o[3] = (unsigned)f2bf(v1.z) | ((unsigned)f2bf(v1.w) << 16);
        *(uint4*)(xb + i * 8) = *(uint4*)o;
        return;
    }
    // prep_w: m: 0-2 W_lin, 3-5 W_msg(top 128), 6-8 W_l, 9-11 W_r, 12 W_dec, 13 W_fin(C=64)
    const int local = b - ncast;
    const int m = local >> 6;
    const float* src; int C = 128;
    if      (m < 3)  src = Wlin + m * 16384;
    else if (m < 6)  src = Wmsg + (m - 3) * (129 * 128);
    else if (m < 9)  src = Wl   + (m - 6) * 16384;
    else if (m < 12) src = Wr   + (m - 9) * 16384;
    else if (m == 12) src = Wdec;
    else { src = Wfin; C = 64; }
    const int elems = C * 128;
    const int e = (local & 63) * 256 + threadIdx.x;
    if (e >= elems) return;
    const int c = e >> 7, k = e & 127;
    wt[m * 16384 + e] = f2bf(src[k * C + c]);
}

// ---- U2: chunksum ∪ chain0 ----
__global__ __launch_bounds__(256)
void k_u2(const int* __restrict__ deg, int* __restrict__ csum, int nch,
          const unsigned short* __restrict__ A, const unsigned short* __restrict__ Wt1,
          const unsigned short* __restrict__ Wtc, const float* __restrict__ b1,
          const float* __restrict__ b2, unsigned short* __restrict__ Out, int n)
{
    __shared__ __align__(16) unsigned short As1[64 * HD];
    __shared__ __align__(16) unsigned short Hs [64 * HD];
    if ((int)blockIdx.x < nch) {
        __shared__ int s[256];
        const int t = threadIdx.x, i = blockIdx.x * 256 + t;
        s[t] = (i < n) ? deg[i] : 0;
        __syncthreads();
        for (int o = 128; o > 0; o >>= 1) { if (t < o) s[t] += s[t + o]; __syncthreads(); }
        if (t == 0) csum[blockIdx.x] = s[0];
        return;
    }
    dev_chain(As1, Hs, A, Wt1, Wtc, b1, b2, Out, n, blockIdx.x - nch);
}

// ---- scans ----
__global__ void k_scanmid(const int* __restrict__ csum, int* __restrict__ cbase,
                          int* __restrict__ rowstart, int nch, int n) {
    __shared__ int s[512];
    int t = threadIdx.x;
    int v = (t < nch) ? csum[t] : 0;
    s[t] = v; __syncthreads();
    for (int off = 1; off < 512; off <<= 1) {
        int tmp = (t >= off) ? s[t - off] : 0;
        __syncthreads();
        s[t] += tmp;
        __syncthreads();
    }
    if (t < nch) cbase[t] = s[t] - v;
    if (t == nch - 1) rowstart[n] = s[t];
}

__global__ void k_scan2(const int* __restrict__ deg, const int* __restrict__ cbase,
                        int* __restrict__ rowstart, float* __restrict__ inv_deg, int n) {
    __shared__ int s[256];
    int t = threadIdx.x, i = blockIdx.x * 256 + t;
    int v = (i < n) ? deg[i] : 0;
    s[t] = v; __syncthreads();
    for (int off = 1; off < 256; off <<= 1) {
        int tmp = (t >= off) ? s[t - off] : 0;
        __syncthreads();
        s[t] += tmp;
        __syncthreads();
    }
    if (i < n) {
        rowstart[i] = cbase[blockIdx.x] + s[t] - v;
        inv_deg[i] = 1.0f / fmaxf((float)v, 1.0f);
    }
}

// agg[i] = bf16( inv_deg[i] * sum_p relu(g[src_p] + attr_p * wlast) )
// 16 lanes/node, 16B/lane, 4-edge unroll.
__global__ __launch_bounds__(256)
void k_agg(const unsigned short* __restrict__ g, const uint2* __restrict__ rec,
           const int* __restrict__ rs, const float* __restrict__ inv_deg,
           const float* __restrict__ wlast, unsigned short* __restrict__ agg, int n) {
    const int lane = threadIdx.x & 15;
    const int node = blockIdx.x * 16 + (threadIdx.x >> 4);
    if (node >= n) return;
    const int c0 = lane * 8;
    const float4 wla = *(const float4*)(wlast + c0);
    const float4 wlb = *(const float4*)(wlast + c0 + 4);
    const int p0 = rs[node], p1 = rs[node + 1];
    float a0=0,a1=0,a2=0,a3=0,a4=0,a5=0,a6=0,a7=0;
    int p = p0;
    for (; p + 4 <= p1; p += 4) {
        uint2 r[4];
#pragma unroll
        for (int u = 0; u < 4; ++u) r[u] = rec[p + u];
        uint4 G[4];
#pragma unroll
        for (int u = 0; u < 4; ++u) G[u] = *(const uint4*)(g + (long)r[u].x * HD + c0);
#pragma unroll
        for (int u = 0; u < 4; ++u) {
            const float e = __builtin_bit_cast(float, r[u].y);
            a0 += fmaxf(fmaf(e, wla.x, bflo(G[u].x)), 0.f);
            a1 += fmaxf(fmaf(e, wla.y, bfhi(G[u].x)), 0.f);
            a2 += fmaxf(fmaf(e, wla.z, bflo(G[u].y)), 0.f);
            a3 += fmaxf(fmaf(e, wla.w, bfhi(G[u].y)), 0.f);
            a4 += fmaxf(fmaf(e, wlb.x, bflo(G[u].z)), 0.f);
            a5 += fmaxf(fmaf(e, wlb.y, bfhi(G[u].z)), 0.f);
            a6 += fmaxf(fmaf(e, wlb.z, bflo(G[u].w)), 0.f);
            a7 += fmaxf(fmaf(e, wlb.w, bfhi(G[u].w)), 0.f);
        }
    }
    for (; p < p1; ++p) {
        const uint2 r0 = rec[p];
        const float e0 = __builtin_bit_cast(float, r0.y);
        const uint4 G0 = *(const uint4*)(g + (long)r0.x * HD + c0);
        a0 += fmaxf(fmaf(e0, wla.x, bflo(G0.x)), 0.f);
        a1 += fmaxf(fmaf(e0, wla.y, bfhi(G0.x)), 0.f);
        a2 += fmaxf(fmaf(e0, wla.z, bflo(G0.y)), 0.f);
        a3 += fmaxf(fmaf(e0, wla.w, bfhi(G0.y)), 0.f);
        a4 += fmaxf(fmaf(e0, wlb.x, bflo(G0.z)), 0.f);
        a5 += fmaxf(fmaf(e0, wlb.y, bfhi(G0.z)), 0.f);
        a6 += fmaxf(fmaf(e0, wlb.z, bflo(G0.w)), 0.f);
        a7 += fmaxf(fmaf(e0, wlb.w, bfhi(G0.w)), 0.f);
    }
    const float id = inv_deg[node];
    uint4 o;
    o.x = (unsigned)f2bf(a0 * id) | ((unsigned)f2bf(a1 * id) << 16);
    o.y = (unsigned)f2bf(a2 * id) | ((unsigned)f2bf(a3 * id) << 16);
    o.z = (unsigned)f2bf(a4 * id) | ((unsigned)f2bf(a5 * id) << 16);
    o.w = (unsigned)f2bf(a6 * id) | ((unsigned)f2bf(a7 * id) << 16);
    *(uint4*)(agg + (long)node * HD + c0) = o;
}

extern "C" void kernel_launch(void* const* d_in, const int* in_sizes, int n_in,
                              void* d_out, int out_size, void* d_ws, size_t ws_size,
                              hipStream_t stream)
{
    const float* x     = (const float*)d_in[0];
    const float* eattr = (const float*)d_in[1];
    const float* W_lin = (const float*)d_in[2];
    const float* b_lin = (const float*)d_in[3];
    const float* W_msg = (const float*)d_in[4];
    const float* b_msg = (const float*)d_in[5];
    const float* W_l   = (const float*)d_in[6];
    const float* b_l   = (const float*)d_in[7];
    const float* W_r   = (const float*)d_in[8];
    const float* W_dec = (const float*)d_in[9];
    const float* b_dec = (const float*)d_in[10];
    const float* W_fin = (const float*)d_in[11];
    const float* b_fin = (const float*)d_in[12];
    const int*   ei    = (const int*)d_in[13];

    const int N = in_sizes[0] / HD;   // 100000
    const int E = in_sizes[1];        // 600000
    const int* srcv = ei;
    const int* dstv = ei + E;

    char* wsb = (char*)d_ws;
    size_t off = 0;
    auto carve = [&](size_t bytes) -> void* {
        void* p = wsb + off;
        off += (bytes + 255) & ~(size_t)255;
        return p;
    };
    unsigned short* xb = (unsigned short*)carve((size_t)N * HD * 2);
    unsigned short* t1 = (unsigned short*)carve((size_t)N * HD * 2);
    unsigned short* t2 = (unsigned short*)carve((size_t)N * HD * 2);
    unsigned short* t3 = (unsigned short*)carve((size_t)N * HD * 2);
    unsigned short* wt = (unsigned short*)carve((size_t)14 * 16384 * 2);
    uint2* csr_rec  = (uint2*)carve((size_t)E * 8);
    int*   rowstart = (int*)carve((size_t)(N + 1) * 4);
    int*   deg      = (int*)carve((size_t)N * 4);
    float* inv_deg  = (float*)carve((size_t)N * 4);
    const int NCH = (N + 255) / 256;
    int* csum  = (int*)carve((size_t)NCH * 4);
    int* cbase = (int*)carve((size_t)NCH * 4);

    if (off > ws_size) {
        hipMemsetAsync(d_out, 0, (size_t)out_size * 4, stream);
        return;
    }

    hipMemsetAsync(deg, 0, (size_t)N * 4, stream);

    auto WT = [&](int m) { return wt + (size_t)m * 16384; };
    const int NB64 = (N + 63) / 64;
    const int GAGG = (N + 15) / 16;
    const long n8 = (long)N * HD / 8;
    const int ncast = (int)((n8 + 255) / 256);

    // U1: deg (4096 scatter blocks) ∪ cast ∪ prep_w
    k_u1<<<NBLK_SCAT + ncast + 14 * 64, 256, 0, stream>>>(
        dstv, deg, E, x, xb, n8, ncast, W_lin, W_msg, W_l, W_r, W_dec, W_fin, wt, N);
    // U2: chunksum ∪ chain0 (xb -> g0 in t2)
    k_u2<<<NCH + NB64, 256, 0, stream>>>(
        deg, csum, NCH, xb, WT(0), WT(3), b_lin, b_msg, t2, N);
    k_scanmid<<<1, 512, 0, stream>>>(csum, cbase, rowstart, NCH, N);
    k_scan2<<<NCH, 256, 0, stream>>>(deg, cbase, rowstart, inv_deg, N);
    // fill: standalone, LDS-free, 4096 blocks
    k_fill<<<NBLK_SCAT, 256, 0, stream>>>(srcv, dstv, eattr, rowstart, deg, csr_rec, E, N);

    auto wlast = [&](int l) { return W_msg + (size_t)l * (HD + 1) * HD + (size_t)HD * HD; };

    // Alias-free rotation: x path xb -> t3 -> xb ; g -> t2 ; agg -> t1.
    // agg0: g0(t2) -> t1
    k_agg<<<GAGG, 256, 0, stream>>>(t2, csr_rec, rowstart, inv_deg, wlast(0), t1, N);
    // dualchain l0->l1: Agg=t1, X=xb -> x1=t3, g1=t2 (g0 dead)
    k_dualchain<<<NB64, 256, 0, stream>>>(
        t1, xb, WT(6), WT(9), b_l, WT(1), b_lin + HD, WT(4), b_msg + HD, t3, t2, N);
    // agg1: g1(t2) -> t1 (agg0 dead)
    k_agg<<<GAGG, 256, 0, stream>>>(t2, csr_rec, rowstart, inv_deg, wlast(1), t1, N);
    // dualchain l1->l2: Agg=t1, X=t3 -> x2=xb (xb dead), g2=t2 (g1 dead)
    k_dualchain<<<NB64, 256, 0, stream>>>(
        t1, t3, WT(7), WT(10), b_l + HD, WT(2), b_lin + 2 * HD, WT(5), b_msg + 2 * HD, xb, t2, N);
    // agg2: g2(t2) -> t1 (agg1 dead)
    k_agg<<<GAGG, 256, 0, stream>>>(t2, csr_rec, rowstart, inv_deg, wlast(2), t1, N);
    // dual2 + decoder: Agg=t1, X=xb -> d_out
    k_dualdec<<<NB64, 256, 0, stream>>>(t1, xb, WT(8), WT(11), b_l + 2 * HD,
                                        WT(12), b_dec, WT(13), b_fin, (float*)d_out, N);
}